// Round 9
// baseline (75.764 us; speedup 1.0000x reference)
//
#include <hip/hip_runtime.h>
#include <hip/hip_bf16.h>

// GraphConvolution: out[b] = adj[b] @ (feat[b] @ W) + bias
// B=32, N=1024, IN=256, OUT=256. fp32 in/out, bf16 MFMA internally.
//
// ws: [0,128KB)  Wt = W^T bf16, k-subtiled: [k>>3][n=256][8]
//     [128KB..)  St = support bf16, k-subtiled per batch: [b][m>>3][n=256][8]
//
// Round-9: TLP. r6-r8 all ran 1 block/CU (grid 256, LDS 96KB) -> one barrier
// domain per CU, every stall is a full-CU convoy. New geometry:
//   128x128 tile, 256 thr (4 waves 2x2, 64x64 wave tiles — same LDS-read/FLOP
//   as 2x4@256), BK=64, 32x32x16 MFMA, A SINGLE-buffered (CVTW after mid-tile
//   lgkm0+barrier), B double-buffered -> LDS 48 KB, grid 512 -> 2 independent
//   blocks/CU: one block computes while the other waits its DMA (m114).
// Counted syncs kept (T4): per tile "vmcnt(8); s_barrier" certifies B(t+1)
// (oldest 4 vmem) while A(t+2) (8 loads) stays in flight. Never drains in
// the main loop.
// 32x32x16 layouts: A/B: lane&31 = row/col, k-chunk (lane>>5)*8 (contig 8);
// C/D: col=lane&31, row=(reg&3)+8*(reg>>2)+4*(lane>>5)  [m74/m101].

typedef __attribute__((__ext_vector_type__(4)))  float  f32x4;
typedef __attribute__((__ext_vector_type__(16))) float  f32x16;
typedef __attribute__((__ext_vector_type__(8)))  __bf16 bf16x8;
typedef __attribute__((__ext_vector_type__(4)))  __bf16 bf16x4;

#define BK 64

__device__ __forceinline__ void gld16(const void* g, void* l) {
  __builtin_amdgcn_global_load_lds(
      (const __attribute__((address_space(1))) unsigned int*)g,
      (__attribute__((address_space(3))) unsigned int*)l, 16, 0, 0);
}

// ---- weight transpose: w[k][n] fp32 -> Wt k-subtiled [k>>3][n][8] bf16 -----
__global__ __launch_bounds__(256) void k_wt(const float* __restrict__ w,
                                            __bf16* __restrict__ Wt) {
  __shared__ __bf16 T[64][65];
  const int bi = blockIdx.x >> 2;  // k tile
  const int bj = blockIdx.x & 3;   // n tile
  const int t  = threadIdx.x;
  const int r  = t >> 2;
  const int q  = t & 3;
  const float* src = w + (size_t)(bi * 64 + r) * 256 + bj * 64 + q * 16;
#pragma unroll
  for (int u = 0; u < 4; ++u) {
    f32x4 v = *(const f32x4*)(src + u * 4);
    T[r][q * 16 + u * 4 + 0] = (__bf16)v[0];
    T[r][q * 16 + u * 4 + 1] = (__bf16)v[1];
    T[r][q * 16 + u * 4 + 2] = (__bf16)v[2];
    T[r][q * 16 + u * 4 + 3] = (__bf16)v[3];
  }
  __syncthreads();
  bf16x8 h0, h1;
#pragma unroll
  for (int u = 0; u < 8; ++u) {
    h0[u] = T[q * 16 + u][r];      // k = bi*64+q*16+u,   n = bj*64+r
    h1[u] = T[q * 16 + 8 + u][r];  // k = bi*64+q*16+8+u
  }
  __bf16* d0 = Wt + ((size_t)(bi * 8 + q * 2) * 256 + (bj * 64 + r)) * 8;
  *(bf16x8*)d0          = h0;
  *(bf16x8*)(d0 + 2048) = h1;
}

// ---- main GEMM: 128x128 tile, BK=64, 256 thr (4 waves 2x2), 32x32x16 -------
// EPI_ST=true : epilogue -> St k-subtiled bf16 (gemm1: feat @ W)
// EPI_ST=false: epilogue -> Out fp32 + bias, XCD swizzle (gemm2)
template <int KTOT, int LDA, bool EPI_ST>
__global__ __launch_bounds__(256, 2) void k_gemm(
    const float* __restrict__ Aall, const __bf16* __restrict__ Bg_all,
    const float* __restrict__ bias, float* __restrict__ Out,
    __bf16* __restrict__ St) {
  __shared__ __bf16 Af[128 * 64];      // 16 KB single buf: [row][slot^(row&7)][8]
  __shared__ __bf16 Bf[2][8 * 128 * 8];// 16 KB each: [chunk][colx][8]

  const int tid  = threadIdx.x;
  const int lane = tid & 63;
  const int wid  = tid >> 6;       // 0..3
  const int wm   = (wid >> 1) * 64;
  const int wn   = (wid & 1) * 64;
  const int l31  = lane & 31;
  const int hi   = lane >> 5;      // k-half 0/1

  int b, mblk, nh;
  const float*  Ablk;
  const __bf16* Bblk;
  if constexpr (EPI_ST) {
    const int bx = blockIdx.x;     // 512 blocks: 256 m-tiles x 2 n-halves
    const int mt_lin = bx >> 1;    // feat rows globally contiguous
    nh   = bx & 1;
    b    = mt_lin >> 3;
    mblk = mt_lin & 7;
    Ablk = Aall + (size_t)mt_lin * 128 * LDA;
    Bblk = Bg_all;                 // Wt
  } else {
    const int h  = blockIdx.x;     // 512 % 8 == 0: bijective XCD swizzle
    const int lg = (h & 7) * 64 + (h >> 3);  // XCD x owns batches 4x..4x+3
    b    = lg >> 4;
    mblk = (lg >> 1) & 7;
    nh   = lg & 1;
    Ablk = Aall + (size_t)b * 1024 * 1024 + (size_t)mblk * 128 * LDA;
    Bblk = Bg_all + (size_t)b * 262144;      // St[b], k-subtiled
  }
  const int nb0 = nh * 128;

  // --- A staging (reg): thread t -> row=t>>1, k-quarter (t&1)*32 ---
  const int    srow = tid >> 1;
  const int    skq  = (tid & 1) * 32;
  const float* asrc = Ablk + (size_t)srow * LDA + skq;
  const int    sr7  = srow & 7;

  // --- B staging (DMA): thread t: chunks lin=i*256+t of 16B each ---
  const __bf16* bS[4];
#pragma unroll
  for (int i = 0; i < 4; ++i) {
    const int lin = i * 256 + tid;
    bS[i] = Bblk + (size_t)(lin >> 7) * 2048 + (size_t)(nb0 + (lin & 127)) * 8;
  }

  f32x4 S[8];

#define LOADA(k0)                                                             \
  {                                                                           \
    _Pragma("unroll") for (int u = 0; u < 8; ++u)                             \
        S[u] = *(const f32x4*)(asrc + (k0) + u * 4);                          \
  }
#define CVTW()                                                                \
  {                                                                           \
    _Pragma("unroll") for (int u2 = 0; u2 < 4; ++u2) {                        \
      bf16x8 h = {(__bf16)S[2*u2][0],   (__bf16)S[2*u2][1],                   \
                  (__bf16)S[2*u2][2],   (__bf16)S[2*u2][3],                   \
                  (__bf16)S[2*u2+1][0], (__bf16)S[2*u2+1][1],                 \
                  (__bf16)S[2*u2+1][2], (__bf16)S[2*u2+1][3]};                \
      const int slot = (((tid & 1) * 4 + u2) ^ sr7);                          \
      *(bf16x8*)&Af[srow * 64 + slot * 8] = h;                                \
    }                                                                         \
  }
#define ISSUEB(buf, k0)                                                       \
  {                                                                           \
    const size_t koff = (size_t)((k0) >> 3) * 2048;                           \
    _Pragma("unroll") for (int i = 0; i < 4; ++i)                             \
        gld16(bS[i] + koff, &Bf[buf][(i * 256 + wid * 64) * 8]);              \
    asm volatile("" ::: "memory");                                            \
  }
#define MIDBAR asm volatile("s_waitcnt lgkmcnt(0)\n\ts_barrier" ::: "memory")
#define SYNC8  asm volatile("s_waitcnt vmcnt(8) lgkmcnt(0)\n\ts_barrier" ::: "memory")
#define SYNC0  asm volatile("s_waitcnt vmcnt(0) lgkmcnt(0)\n\ts_barrier" ::: "memory")

  f32x16 acc[2][2];
#pragma unroll
  for (int mi = 0; mi < 2; ++mi)
#pragma unroll
    for (int ni = 0; ni < 2; ++ni)
#pragma unroll
      for (int r = 0; r < 16; ++r) acc[mi][ni][r] = 0.f;

  auto dsread = [&](int p, int ks, bf16x8* af, bf16x8* bv) {
#pragma unroll
    for (int mi = 0; mi < 2; ++mi) {
      const int row  = wm + mi * 32 + l31;
      const int slot = (ks * 2 + hi) ^ (row & 7);
      af[mi] = *(const bf16x8*)&Af[row * 64 + slot * 8];
    }
#pragma unroll
    for (int ni = 0; ni < 2; ++ni) {
      const int colx = wn + ni * 32 + l31;
      bv[ni] = *(const bf16x8*)&Bf[p][((ks * 2 + hi) * 128 + colx) * 8];
    }
  };
  auto domfma = [&](const bf16x8* af, const bf16x8* bv) {
    __builtin_amdgcn_s_setprio(1);
#pragma unroll
    for (int mi = 0; mi < 2; ++mi)
#pragma unroll
      for (int ni = 0; ni < 2; ++ni)
        acc[mi][ni] = __builtin_amdgcn_mfma_f32_32x32x16_bf16(af[mi], bv[ni], acc[mi][ni], 0, 0, 0);
    __builtin_amdgcn_s_setprio(0);
  };

  constexpr int NT = KTOT / BK;    // 16 (gemm2) or 4 (gemm1), even
  // prologue: A(0)->regs->Af; B(0) DMA; A(1)->regs; counted sync
  LOADA(0);
  ISSUEB(0, 0);
  CVTW();                          // reg-dep drains A(0); B(0) keeps flying
  LOADA(BK);
  SYNC8;                           // outstanding B(0)4+A(1)8=12 -> B(0) done

  for (int t = 0; t < NT - 2; ++t) {
    const int p = t & 1;
    ISSUEB(p ^ 1, (t + 1) * BK);   // B(t+1) -> other buf (freed at last bar)
    bf16x8 af[2], bv[2];
    dsread(p, 0, af, bv); domfma(af, bv);
    dsread(p, 1, af, bv); domfma(af, bv);
    dsread(p, 2, af, bv); domfma(af, bv);
    dsread(p, 3, af, bv);          // last reads of Af for tile t
    MIDBAR;                        // all waves' A-reads landed in regs
    CVTW();                        // A(t+1) -> Af (reg-dep: waits its 8 loads)
    LOADA((t + 2) * BK);           // A(t+2): 8 loads fly through next sync
    domfma(af, bv);                // ks3 MFMA under the staging
    SYNC8;                         // B(t+1) (oldest 4) done; A(t+2) flying
  }
  {                                // t = NT-2  (p = 0 since NT even)
    ISSUEB(1, (NT - 1) * BK);
    bf16x8 af[2], bv[2];
    dsread(0, 0, af, bv); domfma(af, bv);
    dsread(0, 1, af, bv); domfma(af, bv);
    dsread(0, 2, af, bv); domfma(af, bv);
    dsread(0, 3, af, bv);
    MIDBAR;
    CVTW();                        // A(NT-1) -> Af
    domfma(af, bv);
    SYNC0;                         // drain B(NT-1)
  }
  {                                // tail t = NT-1 (buf 1), compute only
    bf16x8 af[2], bv[2];
    dsread(1, 0, af, bv); domfma(af, bv);
    dsread(1, 1, af, bv); domfma(af, bv);
    dsread(1, 2, af, bv); domfma(af, bv);
    dsread(1, 3, af, bv); domfma(af, bv);
  }

#undef LOADA
#undef CVTW
#undef ISSUEB
#undef MIDBAR
#undef SYNC8
#undef SYNC0

  // --- epilogue. 32x32 C/D: col=lane&31, row=(reg&3)+8*(reg>>2)+4*hi ---
  if constexpr (EPI_ST) {
    __bf16* Stb = St + (size_t)b * 262144;
    const int gmbase = mblk * 128 + wm;   // multiple of 32
#pragma unroll
    for (int mi = 0; mi < 2; ++mi) {
      const int base3 = ((gmbase + mi * 32) >> 3);
#pragma unroll
      for (int ni = 0; ni < 2; ++ni) {
        const int col = nb0 + wn + ni * 32 + l31;
#pragma unroll
        for (int rq = 0; rq < 4; ++rq) {
          bf16x4 hh = {(__bf16)acc[mi][ni][rq * 4 + 0],
                       (__bf16)acc[mi][ni][rq * 4 + 1],
                       (__bf16)acc[mi][ni][rq * 4 + 2],
                       (__bf16)acc[mi][ni][rq * 4 + 3]};
          __bf16* dst = Stb + (size_t)(base3 + rq) * 2048 + (size_t)col * 8 + 4 * hi;
          *(bf16x4*)dst = hh;
        }
      }
    }
  } else {
    float* ob = Out + ((size_t)b * 1024 + (size_t)mblk * 128 + wm) * 256;
#pragma unroll
    for (int mi = 0; mi < 2; ++mi)
#pragma unroll
      for (int ni = 0; ni < 2; ++ni) {
        const int col = nb0 + wn + ni * 32 + l31;
        const float bvs = bias[col];
#pragma unroll
        for (int rq = 0; rq < 4; ++rq)
#pragma unroll
          for (int j = 0; j < 4; ++j) {
            const int row = mi * 32 + rq * 8 + 4 * hi + j;
            ob[(size_t)row * 256 + col] = acc[mi][ni][rq * 4 + j] + bvs;
          }
      }
  }
}

extern "C" void kernel_launch(void* const* d_in, const int* in_sizes, int n_in,
                              void* d_out, int out_size, void* d_ws, size_t ws_size,
                              hipStream_t stream) {
  const float* adj  = (const float*)d_in[0];
  const float* feat = (const float*)d_in[1];
  const float* w    = (const float*)d_in[2];
  const float* bias = (const float*)d_in[3];
  float* out = (float*)d_out;

  __bf16* Wt = (__bf16*)d_ws;                    // 128 KB
  __bf16* St = (__bf16*)((char*)d_ws + 131072);  // 16.78 MB

  k_wt<<<16, 256, 0, stream>>>(w, Wt);
  // gemm1: St = (feat @ W), k-subtiled output  (K=256, A ld 256)
  k_gemm<256, 256, true><<<512, 256, 0, stream>>>(feat, Wt, nullptr, nullptr, St);
  // gemm2: out = adj @ support + bias          (K=1024, A ld 1024)
  k_gemm<1024, 1024, false><<<512, 256, 0, stream>>>(adj, St, bias, out, nullptr);
}

// Round 10
// 54.794 us; speedup vs baseline: 1.3827x; 1.3827x over previous
//
#include <hip/hip_runtime.h>
#include <hip/hip_bf16.h>

// GraphConvolution: out[b] = adj[b] @ (feat[b] @ W) + bias
// B=32, N=1024, IN=256, OUT=256. fp32 in/out, bf16 MFMA internally.
//
// ws: [0,128KB)  Wt = W^T bf16, k-subtiled: [k>>3][n=256][8]
//     [128KB..)  St = support bf16, k-subtiled per batch: [b][m>>3][n=256][8]
//
// Round-10: r8 geometry (128x256 tile, BK=64, 8 waves 2x4, A reg-staged with
// XOR swizzle, B via global_load_lds, 96 KB LDS dbuf, XCD swizzle) + the
// m201-style fine phase schedule (T3+T4): per K-tile two phases, each
//   { ds_read half-tile  ||  stage-issue }  -> s_barrier -> lgkmcnt(0)
//   -> sched_barrier(0) -> setprio(1) 16x MFMA setprio(0) -> s_barrier
// with counted vmcnt(4) ONLY at tile end (B(t+1)=oldest-4 certified; A(t+2)
// stays in flight). Loop unrolled x2 so reg-sets/buffers are static.

typedef __attribute__((__ext_vector_type__(4))) float  f32x4;
typedef __attribute__((__ext_vector_type__(8))) __bf16 bf16x8;
typedef __attribute__((__ext_vector_type__(4))) __bf16 bf16x4;

#define BK 64

__device__ __forceinline__ void gld16(const void* g, void* l) {
  __builtin_amdgcn_global_load_lds(
      (const __attribute__((address_space(1))) unsigned int*)g,
      (__attribute__((address_space(3))) unsigned int*)l, 16, 0, 0);
}

// ---- weight transpose: w[k][n] fp32 -> Wt k-subtiled [k>>3][n][8] bf16 -----
__global__ __launch_bounds__(256) void k_wt(const float* __restrict__ w,
                                            __bf16* __restrict__ Wt) {
  __shared__ __bf16 T[64][65];
  const int bi = blockIdx.x >> 2;  // k tile
  const int bj = blockIdx.x & 3;   // n tile
  const int t  = threadIdx.x;
  const int r  = t >> 2;
  const int q  = t & 3;
  const float* src = w + (size_t)(bi * 64 + r) * 256 + bj * 64 + q * 16;
#pragma unroll
  for (int u = 0; u < 4; ++u) {
    f32x4 v = *(const f32x4*)(src + u * 4);
    T[r][q * 16 + u * 4 + 0] = (__bf16)v[0];
    T[r][q * 16 + u * 4 + 1] = (__bf16)v[1];
    T[r][q * 16 + u * 4 + 2] = (__bf16)v[2];
    T[r][q * 16 + u * 4 + 3] = (__bf16)v[3];
  }
  __syncthreads();
  bf16x8 h0, h1;
#pragma unroll
  for (int u = 0; u < 8; ++u) {
    h0[u] = T[q * 16 + u][r];      // k = bi*64+q*16+u,   n = bj*64+r
    h1[u] = T[q * 16 + 8 + u][r];  // k = bi*64+q*16+8+u
  }
  __bf16* d0 = Wt + ((size_t)(bi * 8 + q * 2) * 256 + (bj * 64 + r)) * 8;
  *(bf16x8*)d0          = h0;
  *(bf16x8*)(d0 + 2048) = h1;
}

// ---- main GEMM: 128x256 tile, BK=64, 512 thr (8 waves 2x4) -----------------
template <int KTOT, int LDA, bool EPI_ST>
__global__ __launch_bounds__(512, 2) void k_gemm(
    const float* __restrict__ Aall, const __bf16* __restrict__ Bg_all,
    const float* __restrict__ bias, float* __restrict__ Out,
    __bf16* __restrict__ St) {
  __shared__ __bf16 Af[2][128 * 64];     // 16 KB each: [row][slot^(row&7)][8]
  __shared__ __bf16 Bf[2][8 * 256 * 8];  // 32 KB each: [chunk][n][8]

  const int tid  = threadIdx.x;
  const int lane = tid & 63;
  const int wid  = tid >> 6;       // 0..7
  const int wr   = wid >> 2;       // 0..1 -> m offset *64
  const int wc   = wid & 3;        // 0..3 -> n offset *64
  const int l16  = lane & 15;
  const int g    = lane >> 4;      // 0..3

  int b, mblk;
  const float*  Ablk;
  const __bf16* Bblk;
  if constexpr (EPI_ST) {
    const int bx = blockIdx.x;     // 256 blocks: feat rows globally contiguous
    b    = bx >> 3;
    mblk = bx & 7;
    Ablk = Aall + (size_t)bx * 128 * LDA;
    Bblk = Bg_all;                 // Wt
  } else {
    const int h  = blockIdx.x;     // 256 % 8 == 0: bijective XCD swizzle
    const int lg = (h & 7) * 32 + (h >> 3);  // XCD x owns batches 4x..4x+3
    b    = lg >> 3;
    mblk = lg & 7;
    Ablk = Aall + (size_t)b * 1024 * 1024 + (size_t)mblk * 128 * LDA;
    Bblk = Bg_all + (size_t)b * 262144;      // St[b], k-subtiled
  }

  // --- A staging (reg): thread t -> row=t>>2, k-cols (t&3)*16..+15 ---
  const int    srow = tid >> 2;
  const int    sq   = tid & 3;
  const float* asrc = Ablk + (size_t)srow * LDA + sq * 16;
  const int wof0 = srow * 64 + (((sq * 2)     ^ (srow & 7)) << 3);
  const int wof1 = srow * 64 + (((sq * 2 + 1) ^ (srow & 7)) << 3);

  // --- B staging (DMA): thread t handles chunks {i*512+t} of 16 B ---
  const __bf16* bS[4];
#pragma unroll
  for (int i = 0; i < 4; ++i) bS[i] = Bblk + (size_t)(i * 512 + tid) * 8;

#define LOADA(S, k0)                                                          \
  {                                                                           \
    _Pragma("unroll") for (int u = 0; u < 4; ++u)                             \
        S[u] = *(const f32x4*)(asrc + (k0) + u * 4);                          \
  }
#define ISSUEB(buf, k0)                                                       \
  {                                                                           \
    const size_t koff = (size_t)((k0) >> 3) * 2048;                           \
    _Pragma("unroll") for (int i = 0; i < 4; ++i)                             \
        gld16(bS[i] + koff, &Bf[buf][(i * 512 + wid * 64) * 8]);              \
    asm volatile("" ::: "memory");                                            \
  }
#define CVTW(S, buf)                                                          \
  {                                                                           \
    bf16x8 h0 = {(__bf16)S[0][0], (__bf16)S[0][1], (__bf16)S[0][2],           \
                 (__bf16)S[0][3], (__bf16)S[1][0], (__bf16)S[1][1],           \
                 (__bf16)S[1][2], (__bf16)S[1][3]};                           \
    bf16x8 h1 = {(__bf16)S[2][0], (__bf16)S[2][1], (__bf16)S[2][2],           \
                 (__bf16)S[2][3], (__bf16)S[3][0], (__bf16)S[3][1],           \
                 (__bf16)S[3][2], (__bf16)S[3][3]};                           \
    *(bf16x8*)&Af[buf][wof0] = h0;                                            \
    *(bf16x8*)&Af[buf][wof1] = h1;                                            \
  }
// phase entry: all staged LDS traffic retired, pin MFMA after (rule #18)
#define BARIN                                                                 \
  do {                                                                        \
    __builtin_amdgcn_s_barrier();                                             \
    asm volatile("s_waitcnt lgkmcnt(0)" ::: "memory");                        \
    __builtin_amdgcn_sched_barrier(0);                                        \
  } while (0)
#define BAROUT __builtin_amdgcn_s_barrier()
#define GATE4  asm volatile("s_waitcnt vmcnt(4)" ::: "memory")
#define GATE0  asm volatile("s_waitcnt vmcnt(0)" ::: "memory")

  f32x4 S0[4], S1[4];

  f32x4 acc[4][4];
#pragma unroll
  for (int m = 0; m < 4; ++m)
#pragma unroll
    for (int n = 0; n < 4; ++n) acc[m][n] = (f32x4){0.f, 0.f, 0.f, 0.f};

  auto dsread = [&](int p, int ks, bf16x8* af, bf16x8* bv) {
#pragma unroll
    for (int m = 0; m < 4; ++m) {
      const int row  = wr * 64 + m * 16 + l16;
      const int slot = (ks * 4 + g) ^ (row & 7);
      af[m] = *(const bf16x8*)&Af[p][row * 64 + slot * 8];
    }
#pragma unroll
    for (int n = 0; n < 4; ++n) {
      const int col = wc * 64 + n * 16 + l16;
      bv[n] = *(const bf16x8*)&Bf[p][((ks * 4 + g) * 256 + col) * 8];
    }
  };
  auto mfma16 = [&](const bf16x8* af, const bf16x8* bv) {
    __builtin_amdgcn_s_setprio(1);
#pragma unroll
    for (int m = 0; m < 4; ++m)
#pragma unroll
      for (int n = 0; n < 4; ++n)
        acc[m][n] = __builtin_amdgcn_mfma_f32_16x16x32_bf16(af[m], bv[n], acc[m][n], 0, 0, 0);
    __builtin_amdgcn_s_setprio(0);
  };

  constexpr int NT = KTOT / BK;    // 16 (gemm2) or 4 (gemm1), even
  bf16x8 af[4], bv[4];

  // prologue: A(0)->S0->Af[0]; B(0) DMA; A(1)->S1
  LOADA(S0, 0);
  ISSUEB(0, 0);
  LOADA(S1, BK);
  CVTW(S0, 0);                     // compiler waits A(0) regs
  asm volatile("s_waitcnt vmcnt(4) lgkmcnt(0)" ::: "memory");  // B(0) done; A(1) flies
  __builtin_amdgcn_s_barrier();

  for (int t = 0; t < NT - 2; t += 2) {
    // ---- tile t (p=0): Af[0]/Bf[0]; cvt A(t+1)=S1 -> Af[1]; load A(t+2)->S0
    dsread(0, 0, af, bv);
    ISSUEB(1, (t + 1) * BK);       // B(t+1) -> Bf[1]
    BARIN;  mfma16(af, bv);  BAROUT;
    dsread(0, 1, af, bv);
    CVTW(S1, 1);                   // waits A(t+1) regs (auto)
    LOADA(S0, (t + 2) * BK);       // A(t+2): flies through the gate
    BARIN;  mfma16(af, bv);
    GATE4;                         // B(t+1) (oldest 4) done; A(t+2) in flight
    BAROUT;
    // ---- tile t+1 (p=1): Af[1]/Bf[1]; cvt A(t+2)=S0 -> Af[0]; load A(t+3)->S1
    dsread(1, 0, af, bv);
    ISSUEB(0, (t + 2) * BK);       // B(t+2) -> Bf[0]
    BARIN;  mfma16(af, bv);  BAROUT;
    dsread(1, 1, af, bv);
    CVTW(S0, 0);
    LOADA(S1, (t + 3) * BK);
    BARIN;  mfma16(af, bv);
    GATE4;                         // B(t+2) done; A(t+3) in flight
    BAROUT;
  }
  // ---- tile NT-2 (p=0): issue B(NT-1); cvt A(NT-1)=S1 -> Af[1]
  dsread(0, 0, af, bv);
  ISSUEB(1, (NT - 1) * BK);
  BARIN;  mfma16(af, bv);  BAROUT;
  dsread(0, 1, af, bv);
  CVTW(S1, 1);
  BARIN;  mfma16(af, bv);
  GATE0;                           // drain B(NT-1)
  BAROUT;
  // ---- tile NT-1 (p=1): compute only (within-wave lgkm deps auto)
  dsread(1, 0, af, bv);
  mfma16(af, bv);
  dsread(1, 1, af, bv);
  mfma16(af, bv);

#undef LOADA
#undef ISSUEB
#undef CVTW
#undef BARIN
#undef BAROUT
#undef GATE4
#undef GATE0

  // --- epilogue. C/D frag: col = lane&15, row = (lane>>4)*4 + reg ---
  const int rg = g * 4;
  if constexpr (EPI_ST) {
    __bf16* Stb = St + (size_t)b * 262144;
    const int gm0 = mblk * 128 + wr * 64;
#pragma unroll
    for (int n = 0; n < 4; ++n) {
      const int col = wc * 64 + n * 16 + l16;
#pragma unroll
      for (int m = 0; m < 4; ++m) {
        const int gm = gm0 + m * 16 + rg;   // multiple of 4; gm&7 in {0,4}
        __bf16* dst = Stb + (size_t)(gm >> 3) * 2048 + (size_t)col * 8 + (gm & 7);
        bf16x4 hh = {(__bf16)acc[m][n][0], (__bf16)acc[m][n][1],
                     (__bf16)acc[m][n][2], (__bf16)acc[m][n][3]};
        *(bf16x4*)dst = hh;
      }
    }
  } else {
    float* ob = Out + ((size_t)b * 1024 + (size_t)mblk * 128 + wr * 64) * 256;
#pragma unroll
    for (int n = 0; n < 4; ++n) {
      const int col = wc * 64 + n * 16 + l16;
      const float bvs = bias[col];
#pragma unroll
      for (int m = 0; m < 4; ++m) {
        const int row = m * 16 + rg;
#pragma unroll
        for (int r2 = 0; r2 < 4; ++r2)
          ob[(size_t)(row + r2) * 256 + col] = acc[m][n][r2] + bvs;
      }
    }
  }
}

extern "C" void kernel_launch(void* const* d_in, const int* in_sizes, int n_in,
                              void* d_out, int out_size, void* d_ws, size_t ws_size,
                              hipStream_t stream) {
  const float* adj  = (const float*)d_in[0];
  const float* feat = (const float*)d_in[1];
  const float* w    = (const float*)d_in[2];
  const float* bias = (const float*)d_in[3];
  float* out = (float*)d_out;

  __bf16* Wt = (__bf16*)d_ws;                    // 128 KB
  __bf16* St = (__bf16*)((char*)d_ws + 131072);  // 16.78 MB

  k_wt<<<16, 256, 0, stream>>>(w, Wt);
  // gemm1: St = (feat @ W), k-subtiled output  (K=256, A ld 256)
  k_gemm<256, 256, true><<<256, 512, 0, stream>>>(feat, Wt, nullptr, nullptr, St);
  // gemm2: out = adj @ support + bias          (K=1024, A ld 1024)
  k_gemm<1024, 1024, false><<<256, 512, 0, stream>>>(adj, St, bias, out, nullptr);
}

// Round 11
// 53.613 us; speedup vs baseline: 1.4132x; 1.0220x over previous
//
#include <hip/hip_runtime.h>
#include <hip/hip_bf16.h>

// GraphConvolution: out[b] = adj[b] @ (feat[b] @ W) + bias
// B=32, N=1024, IN=256, OUT=256. fp32 in/out, bf16 MFMA internally.
//
// ws: [0,128KB)  Wt = W^T bf16, k-subtiled: [k>>3][n=256][8]
//     [128KB..)  St = support bf16, k-subtiled per batch: [b][m>>3][n=256][8]
//
// Round-11: TLP at traffic-minimal geometry. r6-r10 all ran 1 block/CU
// (2 waves/SIMD, one lockstep barrier domain) -> every latency idles the
// SIMD. r9's TLP attempt paid 2x adjacency traffic (BN=128). Fix both:
//   64x256 block tile (BN=256 full width: adj rows still read ONCE),
//   256 thr / 4 waves (wave tile 64x64 = r8's per-wave shape), BK=32,
//   LDS 42 KB -> grid 512 = 2 INDEPENDENT blocks/CU; counted-vmcnt r8
//   skeleton re-derived for {A=2 loads, B=4 DMAs}/tile (steady gate vmcnt(2)).
// Extras: gemm1 gets the same XCD swizzle -> St[b] produced AND consumed on
// XCD b/4 (L2-local B; previously cross-XCD via L3); nontemporal out stores.
// A staged to [64][40] bf16 rows (pad 40: bank step 20 -> 2-way max, free);
// B via global_load_lds from k-subtiled layout (linear, conflict-free).

typedef __attribute__((__ext_vector_type__(4))) float  f32x4;
typedef __attribute__((__ext_vector_type__(8))) __bf16 bf16x8;
typedef __attribute__((__ext_vector_type__(4))) __bf16 bf16x4;

#define BK 32
#define LDPA 40   // padded A row, elems

__device__ __forceinline__ void gld16(const void* g, void* l) {
  __builtin_amdgcn_global_load_lds(
      (const __attribute__((address_space(1))) unsigned int*)g,
      (__attribute__((address_space(3))) unsigned int*)l, 16, 0, 0);
}

// ---- weight transpose: w[k][n] fp32 -> Wt k-subtiled [k>>3][n][8] bf16 -----
__global__ __launch_bounds__(256) void k_wt(const float* __restrict__ w,
                                            __bf16* __restrict__ Wt) {
  __shared__ __bf16 T[64][65];
  const int bi = blockIdx.x >> 2;  // k tile
  const int bj = blockIdx.x & 3;   // n tile
  const int t  = threadIdx.x;
  const int r  = t >> 2;
  const int q  = t & 3;
  const float* src = w + (size_t)(bi * 64 + r) * 256 + bj * 64 + q * 16;
#pragma unroll
  for (int u = 0; u < 4; ++u) {
    f32x4 v = *(const f32x4*)(src + u * 4);
    T[r][q * 16 + u * 4 + 0] = (__bf16)v[0];
    T[r][q * 16 + u * 4 + 1] = (__bf16)v[1];
    T[r][q * 16 + u * 4 + 2] = (__bf16)v[2];
    T[r][q * 16 + u * 4 + 3] = (__bf16)v[3];
  }
  __syncthreads();
  bf16x8 h0, h1;
#pragma unroll
  for (int u = 0; u < 8; ++u) {
    h0[u] = T[q * 16 + u][r];      // k = bi*64+q*16+u,   n = bj*64+r
    h1[u] = T[q * 16 + 8 + u][r];  // k = bi*64+q*16+8+u
  }
  __bf16* d0 = Wt + ((size_t)(bi * 8 + q * 2) * 256 + (bj * 64 + r)) * 8;
  *(bf16x8*)d0          = h0;
  *(bf16x8*)(d0 + 2048) = h1;
}

// ---- main GEMM: 64x256 tile, BK=32, 256 thr (4 waves 1x4) ------------------
// EPI_ST=true : epilogue -> St k-subtiled bf16 (gemm1: feat @ W)
// EPI_ST=false: epilogue -> Out fp32 + bias (nontemporal), gemm2
template <int KTOT, int LDA, bool EPI_ST>
__global__ __launch_bounds__(256, 4) void k_gemm(
    const float* __restrict__ Aall, const __bf16* __restrict__ Bg_all,
    const float* __restrict__ bias, float* __restrict__ Out,
    __bf16* __restrict__ St) {
  __shared__ __bf16 Af[2][64 * LDPA];    // 5 KB each: [row][k] pad-40
  __shared__ __bf16 Bf[2][4 * 256 * 8];  // 16 KB each: [chunk][n][8]

  const int tid  = threadIdx.x;
  const int lane = tid & 63;
  const int wid  = tid >> 6;       // 0..3
  const int wc   = wid;            // n offset *64 (wave tile 64x64)
  const int l16  = lane & 15;
  const int g    = lane >> 4;      // 0..3

  int b, mblk;
  const float*  Ablk;
  const __bf16* Bblk;
  // XCD swizzle for BOTH gemms (512 % 8 == 0: bijective): XCD x owns
  // lg in [64x, 64x+64) = batches [4x, 4x+4) -> St[b] produced (gemm1)
  // and consumed (gemm2) on the same XCD's L2.
  const int h  = blockIdx.x;
  const int lg = (h & 7) * 64 + (h >> 3);
  b    = lg >> 4;
  mblk = lg & 15;
  if constexpr (EPI_ST) {
    Ablk = Aall + (size_t)lg * 64 * LDA;     // feat rows contiguous by lg
    Bblk = Bg_all;                            // Wt
  } else {
    Ablk = Aall + (size_t)b * 1024 * 1024 + (size_t)mblk * 64 * LDA;
    Bblk = Bg_all + (size_t)b * 262144;       // St[b], k-subtiled, L2-local
  }

  // --- A staging (reg): thread t -> row=t>>2 (64 rows), k-cols (t&2..)*8 ---
  const int    srow = tid >> 2;
  const int    sq   = tid & 3;                 // 8-elem quarter
  const float* asrc = Ablk + (size_t)srow * LDA + sq * 8;
  const int    wof  = srow * LDPA + sq * 8;    // pad-40: 2-way banks max

  // --- B staging (DMA): thread t handles chunks {i*256+t} of 16 B ---
  const __bf16* bS[4];
#pragma unroll
  for (int i = 0; i < 4; ++i) bS[i] = Bblk + (size_t)(i * 256 + tid) * 8;

#define LOADA(S, k0)                                                          \
  {                                                                           \
    S[0] = *(const f32x4*)(asrc + (k0));                                      \
    S[1] = *(const f32x4*)(asrc + (k0) + 4);                                  \
  }
#define ISSUEB(buf, k0)                                                       \
  {                                                                           \
    const size_t koff = (size_t)((k0) >> 3) * 2048;                           \
    _Pragma("unroll") for (int i = 0; i < 4; ++i)                             \
        gld16(bS[i] + koff, &Bf[buf][(i * 256 + wid * 64) * 8]);              \
    asm volatile("" ::: "memory");                                            \
  }
#define CVTW(S, buf)                                                          \
  {                                                                           \
    bf16x8 hh = {(__bf16)S[0][0], (__bf16)S[0][1], (__bf16)S[0][2],           \
                 (__bf16)S[0][3], (__bf16)S[1][0], (__bf16)S[1][1],           \
                 (__bf16)S[1][2], (__bf16)S[1][3]};                           \
    *(bf16x8*)&Af[buf][wof] = hh;                                             \
  }
#define GATE2 asm volatile("s_waitcnt vmcnt(2) lgkmcnt(0)\n\ts_barrier" ::: "memory")
#define GATE6 asm volatile("s_waitcnt vmcnt(6) lgkmcnt(0)\n\ts_barrier" ::: "memory")
#define GATE0 asm volatile("s_waitcnt vmcnt(0) lgkmcnt(0)\n\ts_barrier" ::: "memory")

  f32x4 S0[2], S1[2];

  f32x4 acc[4][4];
#pragma unroll
  for (int m = 0; m < 4; ++m)
#pragma unroll
    for (int n = 0; n < 4; ++n) acc[m][n] = (f32x4){0.f, 0.f, 0.f, 0.f};

  auto compute = [&](int p) {
    bf16x8 af[4], bv[4];
#pragma unroll
    for (int m = 0; m < 4; ++m) {
      const int row = m * 16 + l16;
      af[m] = *(const bf16x8*)&Af[p][row * LDPA + g * 8];
    }
#pragma unroll
    for (int n = 0; n < 4; ++n) {
      const int col = wc * 64 + n * 16 + l16;
      bv[n] = *(const bf16x8*)&Bf[p][(g * 256 + col) * 8];
    }
    __builtin_amdgcn_s_setprio(1);
#pragma unroll
    for (int m = 0; m < 4; ++m)
#pragma unroll
      for (int n = 0; n < 4; ++n)
        acc[m][n] = __builtin_amdgcn_mfma_f32_16x16x32_bf16(af[m], bv[n], acc[m][n], 0, 0, 0);
    __builtin_amdgcn_s_setprio(0);
  };

  constexpr int NT = KTOT / BK;    // 32 (gemm2) or 8 (gemm1), even >= 4
  // prologue. vmem order: A0(2), B0(4), A1(2), B1(4)
  LOADA(S0, 0);
  ISSUEB(0, 0);
  LOADA(S1, BK);
  ISSUEB(1, BK);
  CVTW(S0, 0);                     // waits A0 (oldest 2); B0 keeps flying
  GATE6;                           // drain B0 (oldest 6 done); A1+B1 fly

  for (int t = 0; t < NT - 2; t += 2) {
    // entry: outstanding = A(t+1)(2), B(t+1)(4); Af[0]=t, Bf[0]=B(t)
    compute(0);                    // tile t
    CVTW(S1, 1);                   // waits A(t+1) -> leaves B(t+1)
    LOADA(S0, (t + 2) * BK);       // A(t+2) flies through gate
    GATE2;                         // drain B(t+1); leaves A(t+2)
    ISSUEB(0, (t + 2) * BK);       // buf0 free (barrier passed)

    compute(1);                    // tile t+1
    CVTW(S0, 0);                   // waits A(t+2) -> leaves B(t+2)
    LOADA(S1, (t + 3) * BK);       // A(t+3)
    GATE2;                         // drain B(t+2); leaves A(t+3)
    ISSUEB(1, (t + 3) * BK);
  }
  // tail: Af[0]=NT-2, Bf[0] arrived; outstanding A(NT-1)(2), B(NT-1)(4)
  compute(0);                      // tile NT-2
  CVTW(S1, 1);                     // waits A(NT-1)
  GATE0;                           // drain B(NT-1)
  compute(1);                      // tile NT-1

#undef LOADA
#undef ISSUEB
#undef CVTW
#undef GATE2
#undef GATE6
#undef GATE0

  // --- epilogue. C/D frag: col = lane&15, row = (lane>>4)*4 + reg ---
  const int rg = g * 4;
  if constexpr (EPI_ST) {
    __bf16* Stb = St + (size_t)b * 262144;
    const int gm0 = mblk * 64;
#pragma unroll
    for (int n = 0; n < 4; ++n) {
      const int col = wc * 64 + n * 16 + l16;
#pragma unroll
      for (int m = 0; m < 4; ++m) {
        const int gm = gm0 + m * 16 + rg;   // multiple of 4; gm&7 in {0,4}
        __bf16* dst = Stb + (size_t)(gm >> 3) * 2048 + (size_t)col * 8 + (gm & 7);
        bf16x4 hh = {(__bf16)acc[m][n][0], (__bf16)acc[m][n][1],
                     (__bf16)acc[m][n][2], (__bf16)acc[m][n][3]};
        *(bf16x4*)dst = hh;
      }
    }
  } else {
    float* ob = Out + ((size_t)b * 1024 + (size_t)mblk * 64) * 256;
#pragma unroll
    for (int n = 0; n < 4; ++n) {
      const int col = wc * 64 + n * 16 + l16;
      const float bvs = bias[col];
#pragma unroll
      for (int m = 0; m < 4; ++m) {
        const int row = m * 16 + rg;
#pragma unroll
        for (int r2 = 0; r2 < 4; ++r2)
          __builtin_nontemporal_store(acc[m][n][r2] + bvs,
                                      &ob[(size_t)(row + r2) * 256 + col]);
      }
    }
  }
}

extern "C" void kernel_launch(void* const* d_in, const int* in_sizes, int n_in,
                              void* d_out, int out_size, void* d_ws, size_t ws_size,
                              hipStream_t stream) {
  const float* adj  = (const float*)d_in[0];
  const float* feat = (const float*)d_in[1];
  const float* w    = (const float*)d_in[2];
  const float* bias = (const float*)d_in[3];
  float* out = (float*)d_out;

  __bf16* Wt = (__bf16*)d_ws;                    // 128 KB
  __bf16* St = (__bf16*)((char*)d_ws + 131072);  // 16.78 MB

  k_wt<<<16, 256, 0, stream>>>(w, Wt);
  // gemm1: St = (feat @ W), k-subtiled output  (K=256, A ld 256)
  k_gemm<256, 256, true><<<512, 256, 0, stream>>>(feat, Wt, nullptr, nullptr, St);
  // gemm2: out = adj @ support + bias          (K=1024, A ld 1024)
  k_gemm<1024, 1024, false><<<512, 256, 0, stream>>>(adj, St, bias, out, nullptr);
}

// Round 12
// 53.243 us; speedup vs baseline: 1.4230x; 1.0069x over previous
//
#include <hip/hip_runtime.h>
#include <hip/hip_bf16.h>

// GraphConvolution: out[b] = adj[b] @ (feat[b] @ W) + bias
// B=32, N=1024, IN=256, OUT=256. fp32 in/out, bf16 MFMA internally.
//
// ws: [0,128KB)  Wt = W^T bf16, k-subtiled: [k>>3][n=256][8]
//     [128KB..)  St = support bf16, k-subtiled per batch: [b][m>>3][n=256][8]
//
// Round-12 = r8 (best, 51.6) + TLP at unchanged traffic:
//   BM=128 x BN=256 (adj read once, St read once: 268 MB into CUs — minimal),
//   BK 64->32 halves LDS to 48 KB (A 2x8K + B 2x16K) -> 2 blocks/CU
//   (512 thr, __launch_bounds__(512,4); r8 measured VGPR=48).
//   Two independent barrier domains per CU interleave per-step stalls (m114).
// Counted-vmcnt skeleton re-derived: per tile A=2 reg-loads, B=2 DMAs;
// steady gate vmcnt(2) (B(t+1) certified, A(t+2) flies), prologue vmcnt(4).
// A-swizzle for 64B rows: slot ^= (row>>1)&3 -> 2-way max (free).
// gemm1 now XCD-swizzled too (St produced AND consumed on same XCD's L2);
// out stores nontemporal (don't evict St from L2).

typedef __attribute__((__ext_vector_type__(4))) float  f32x4;
typedef __attribute__((__ext_vector_type__(8))) __bf16 bf16x8;
typedef __attribute__((__ext_vector_type__(4))) __bf16 bf16x4;

#define BK 32

__device__ __forceinline__ void gld16(const void* g, void* l) {
  __builtin_amdgcn_global_load_lds(
      (const __attribute__((address_space(1))) unsigned int*)g,
      (__attribute__((address_space(3))) unsigned int*)l, 16, 0, 0);
}

// ---- weight transpose: w[k][n] fp32 -> Wt k-subtiled [k>>3][n][8] bf16 -----
__global__ __launch_bounds__(256) void k_wt(const float* __restrict__ w,
                                            __bf16* __restrict__ Wt) {
  __shared__ __bf16 T[64][65];
  const int bi = blockIdx.x >> 2;  // k tile
  const int bj = blockIdx.x & 3;   // n tile
  const int t  = threadIdx.x;
  const int r  = t >> 2;
  const int q  = t & 3;
  const float* src = w + (size_t)(bi * 64 + r) * 256 + bj * 64 + q * 16;
#pragma unroll
  for (int u = 0; u < 4; ++u) {
    f32x4 v = *(const f32x4*)(src + u * 4);
    T[r][q * 16 + u * 4 + 0] = (__bf16)v[0];
    T[r][q * 16 + u * 4 + 1] = (__bf16)v[1];
    T[r][q * 16 + u * 4 + 2] = (__bf16)v[2];
    T[r][q * 16 + u * 4 + 3] = (__bf16)v[3];
  }
  __syncthreads();
  bf16x8 h0, h1;
#pragma unroll
  for (int u = 0; u < 8; ++u) {
    h0[u] = T[q * 16 + u][r];      // k = bi*64+q*16+u,   n = bj*64+r
    h1[u] = T[q * 16 + 8 + u][r];  // k = bi*64+q*16+8+u
  }
  __bf16* d0 = Wt + ((size_t)(bi * 8 + q * 2) * 256 + (bj * 64 + r)) * 8;
  *(bf16x8*)d0          = h0;
  *(bf16x8*)(d0 + 2048) = h1;
}

// ---- main GEMM: 128x256 tile, BK=32, 512 thr (8 waves 2x4), 2 blocks/CU ----
// EPI_ST=true : epilogue -> St k-subtiled bf16 (gemm1: feat @ W)
// EPI_ST=false: epilogue -> Out fp32 + bias (nontemporal), gemm2
template <int KTOT, int LDA, bool EPI_ST>
__global__ __launch_bounds__(512, 4) void k_gemm(
    const float* __restrict__ Aall, const __bf16* __restrict__ Bg_all,
    const float* __restrict__ bias, float* __restrict__ Out,
    __bf16* __restrict__ St) {
  __shared__ __bf16 Af[2][128 * 32];     // 8 KB each: [row][slot^((row>>1)&3)][8]
  __shared__ __bf16 Bf[2][4 * 256 * 8];  // 16 KB each: [chunk][n][8]

  const int tid  = threadIdx.x;
  const int lane = tid & 63;
  const int wid  = tid >> 6;       // 0..7
  const int wr   = wid >> 2;       // 0..1 -> m offset *64
  const int wc   = wid & 3;        // 0..3 -> n offset *64
  const int l16  = lane & 15;
  const int g    = lane >> 4;      // 0..3

  // XCD swizzle for BOTH gemms (256 % 8 == 0, bijective): XCD x owns
  // lg in [32x, 32x+32) = batches [4x, 4x+4) -> St[b] produced (gemm1)
  // and consumed (gemm2) on the same XCD's L2.
  const int h  = blockIdx.x;
  const int lg = (h & 7) * 32 + (h >> 3);
  const int b    = lg >> 3;
  const int mblk = lg & 7;
  const float*  Ablk;
  const __bf16* Bblk;
  if constexpr (EPI_ST) {
    Ablk = Aall + (size_t)lg * 128 * LDA;    // feat rows contiguous by lg
    Bblk = Bg_all;                            // Wt
  } else {
    Ablk = Aall + (size_t)b * 1024 * 1024 + (size_t)mblk * 128 * LDA;
    Bblk = Bg_all + (size_t)b * 262144;       // St[b], k-subtiled, L2-local
  }

  // --- A staging (reg): thread t -> row=t>>2, k-quarter (t&3)*8 ---
  const int    srow = tid >> 2;
  const int    sq   = tid & 3;
  const float* asrc = Ablk + (size_t)srow * LDA + sq * 8;
  // 64B rows: swizzle slot ^= (row>>1)&3 -> even-rows spread 4 quads, 2-way max
  const int    wof  = srow * 32 + ((sq ^ ((srow >> 1) & 3)) << 3);

  // --- B staging (DMA): thread t handles chunks {t, 512+t} of 16 B ---
  const __bf16* bS[2];
#pragma unroll
  for (int i = 0; i < 2; ++i) bS[i] = Bblk + (size_t)(i * 512 + tid) * 8;

#define LOADA(S, k0)                                                          \
  {                                                                           \
    S[0] = *(const f32x4*)(asrc + (k0));                                      \
    S[1] = *(const f32x4*)(asrc + (k0) + 4);                                  \
  }
#define ISSUEB(buf, k0)                                                       \
  {                                                                           \
    const size_t koff = (size_t)((k0) >> 3) * 2048;                           \
    _Pragma("unroll") for (int i = 0; i < 2; ++i)                             \
        gld16(bS[i] + koff, &Bf[buf][(i * 512 + wid * 64) * 8]);              \
    asm volatile("" ::: "memory");                                            \
  }
#define CVTW(S, buf)                                                          \
  {                                                                           \
    bf16x8 hh = {(__bf16)S[0][0], (__bf16)S[0][1], (__bf16)S[0][2],           \
                 (__bf16)S[0][3], (__bf16)S[1][0], (__bf16)S[1][1],           \
                 (__bf16)S[1][2], (__bf16)S[1][3]};                           \
    *(bf16x8*)&Af[buf][wof] = hh;                                             \
  }
#define GATE2 asm volatile("s_waitcnt vmcnt(2) lgkmcnt(0)\n\ts_barrier" ::: "memory")
#define GATE4 asm volatile("s_waitcnt vmcnt(4) lgkmcnt(0)\n\ts_barrier" ::: "memory")
#define GATE0 asm volatile("s_waitcnt vmcnt(0) lgkmcnt(0)\n\ts_barrier" ::: "memory")

  f32x4 S0[2], S1[2];

  f32x4 acc[4][4];
#pragma unroll
  for (int m = 0; m < 4; ++m)
#pragma unroll
    for (int n = 0; n < 4; ++n) acc[m][n] = (f32x4){0.f, 0.f, 0.f, 0.f};

  auto compute = [&](int p) {
    bf16x8 af[4], bv[4];
#pragma unroll
    for (int m = 0; m < 4; ++m) {
      const int row  = wr * 64 + m * 16 + l16;
      const int slot = g ^ ((row >> 1) & 3);
      af[m] = *(const bf16x8*)&Af[p][row * 32 + slot * 8];
    }
#pragma unroll
    for (int n = 0; n < 4; ++n) {
      const int col = wc * 64 + n * 16 + l16;
      bv[n] = *(const bf16x8*)&Bf[p][(g * 256 + col) * 8];
    }
    __builtin_amdgcn_s_setprio(1);
#pragma unroll
    for (int m = 0; m < 4; ++m)
#pragma unroll
      for (int n = 0; n < 4; ++n)
        acc[m][n] = __builtin_amdgcn_mfma_f32_16x16x32_bf16(af[m], bv[n], acc[m][n], 0, 0, 0);
    __builtin_amdgcn_s_setprio(0);
  };

  constexpr int NT = KTOT / BK;    // 32 (gemm2) or 8 (gemm1), even
  // prologue. vmem order: A0(2), B0(2), A1(2), B1(2)
  LOADA(S0, 0);
  ISSUEB(0, 0);
  LOADA(S1, BK);
  ISSUEB(1, BK);
  CVTW(S0, 0);                     // reg-dep drains A0; B0,A1,B1 keep flying
  GATE4;                           // B0 done; A1(2)+B1(2) in flight

  for (int t = 0; t < NT - 2; t += 2) {
    // entry: Af[0]=t, Bf[0]=B(t) certified; outstanding A(t+1)2, B(t+1)2
    compute(0);                    // tile t
    CVTW(S1, 1);                   // reg-dep waits A(t+1) -> leaves B(t+1)
    LOADA(S0, (t + 2) * BK);       // A(t+2): flies through the gate
    GATE2;                         // B(t+1) done; A(t+2) in flight
    ISSUEB(0, (t + 2) * BK);       // buf0 free (barrier passed)

    compute(1);                    // tile t+1
    CVTW(S0, 0);                   // waits A(t+2) -> leaves B(t+2)
    LOADA(S1, (t + 3) * BK);       // A(t+3)
    GATE2;                         // B(t+2) done; A(t+3) in flight
    ISSUEB(1, (t + 3) * BK);
  }
  // tail: Af[0]=NT-2, Bf[0] ok; outstanding A(NT-1)2 (S1), B(NT-1)2
  compute(0);                      // tile NT-2
  CVTW(S1, 1);                     // waits A(NT-1)
  GATE0;                           // drain B(NT-1)
  compute(1);                      // tile NT-1

#undef LOADA
#undef ISSUEB
#undef CVTW
#undef GATE2
#undef GATE4
#undef GATE0

  // --- epilogue. C/D frag: col = lane&15, row = (lane>>4)*4 + reg ---
  const int rg = g * 4;
  if constexpr (EPI_ST) {
    __bf16* Stb = St + (size_t)b * 262144;
    const int gm0 = mblk * 128 + wr * 64;
#pragma unroll
    for (int n = 0; n < 4; ++n) {
      const int col = wc * 64 + n * 16 + l16;
#pragma unroll
      for (int m = 0; m < 4; ++m) {
        const int gm = gm0 + m * 16 + rg;   // multiple of 4; gm&7 in {0,4}
        __bf16* dst = Stb + (size_t)(gm >> 3) * 2048 + (size_t)col * 8 + (gm & 7);
        bf16x4 hh = {(__bf16)acc[m][n][0], (__bf16)acc[m][n][1],
                     (__bf16)acc[m][n][2], (__bf16)acc[m][n][3]};
        *(bf16x4*)dst = hh;
      }
    }
  } else {
    float* ob = Out + ((size_t)b * 1024 + (size_t)mblk * 128 + wr * 64) * 256;
#pragma unroll
    for (int n = 0; n < 4; ++n) {
      const int col = wc * 64 + n * 16 + l16;
      const float bvs = bias[col];
#pragma unroll
      for (int m = 0; m < 4; ++m) {
        const int row = m * 16 + rg;
#pragma unroll
        for (int r2 = 0; r2 < 4; ++r2)
          __builtin_nontemporal_store(acc[m][n][r2] + bvs,
                                      &ob[(size_t)(row + r2) * 256 + col]);
      }
    }
  }
}

extern "C" void kernel_launch(void* const* d_in, const int* in_sizes, int n_in,
                              void* d_out, int out_size, void* d_ws, size_t ws_size,
                              hipStream_t stream) {
  const float* adj  = (const float*)d_in[0];
  const float* feat = (const float*)d_in[1];
  const float* w    = (const float*)d_in[2];
  const float* bias = (const float*)d_in[3];
  float* out = (float*)d_out;

  __bf16* Wt = (__bf16*)d_ws;                    // 128 KB
  __bf16* St = (__bf16*)((char*)d_ws + 131072);  // 16.78 MB

  k_wt<<<16, 256, 0, stream>>>(w, Wt);
  // gemm1: St = (feat @ W), k-subtiled output  (K=256, A ld 256)
  k_gemm<256, 256, true><<<256, 512, 0, stream>>>(feat, Wt, nullptr, nullptr, St);
  // gemm2: out = adj @ support + bias          (K=1024, A ld 1024)
  k_gemm<1024, 1024, false><<<256, 512, 0, stream>>>(adj, St, bias, out, nullptr);
}

// Round 13
// 51.409 us; speedup vs baseline: 1.4737x; 1.0357x over previous
//
#include <hip/hip_runtime.h>
#include <hip/hip_bf16.h>

// GraphConvolution: out[b] = adj[b] @ (feat[b] @ W) + bias
// B=32, N=1024, IN=256, OUT=256. fp32 in/out, bf16 MFMA internally.
//
// FINAL (= round-8 kernel, empirical best of 12 structures: 51.56 µs).
// ws: [0,128KB)  Wt = W^T bf16, k-subtiled: [k>>3][n=256][8]
//     [128KB..)  St = support bf16, k-subtiled per batch: [b][m>>3][n=256][8]
//
// Structure: 128x256 block tile (adj read exactly once; St read once), BK=64,
// 8 waves 2x4, LDS 96 KB double-buffered. A reg-staged fp32->bf16 (cvt once)
// with XOR slot^(row&7) swizzled ds_write_b128 (conflict-free write+read);
// B staged via global_load_lds DMA from the k-subtiled bf16 layout (linear,
// coalesced, conflict-free ds_read_b128). Counted-vmcnt sync (T4): one
// barrier per k-step with "s_waitcnt vmcnt(4)" — B(t+1) (oldest 4 vmem ops)
// certified while A(t+2)'s loads stay in flight; never drains to 0 in the
// main loop. T5 setprio around the MFMA cluster. XCD-chunked blockIdx
// swizzle on gemm2 (batch-mates share an XCD's L2 for St[b]).
//
// Traffic ledger (whole graph): ~235 MB compulsory in 51.6 µs = 4.3 TB/s
// sustained vs ~5.5-6.3 TB/s practical stream ceiling -> ~75% of roofline;
// 12 structural variants (barrier-free, fine-phase, TLP, BK=32) all land
// within 51-55 µs, bracketing this as the practical optimum.

typedef __attribute__((__ext_vector_type__(4))) float  f32x4;
typedef __attribute__((__ext_vector_type__(8))) __bf16 bf16x8;
typedef __attribute__((__ext_vector_type__(4))) __bf16 bf16x4;

#define BK 64

__device__ __forceinline__ void gld16(const void* g, void* l) {
  __builtin_amdgcn_global_load_lds(
      (const __attribute__((address_space(1))) unsigned int*)g,
      (__attribute__((address_space(3))) unsigned int*)l, 16, 0, 0);
}

// ---- weight transpose: w[k][n] fp32 -> Wt k-subtiled [k>>3][n][8] bf16 -----
__global__ __launch_bounds__(256) void k_wt(const float* __restrict__ w,
                                            __bf16* __restrict__ Wt) {
  __shared__ __bf16 T[64][65];
  const int bi = blockIdx.x >> 2;  // k tile
  const int bj = blockIdx.x & 3;   // n tile
  const int t  = threadIdx.x;
  const int r  = t >> 2;
  const int q  = t & 3;
  const float* src = w + (size_t)(bi * 64 + r) * 256 + bj * 64 + q * 16;
#pragma unroll
  for (int u = 0; u < 4; ++u) {
    f32x4 v = *(const f32x4*)(src + u * 4);
    T[r][q * 16 + u * 4 + 0] = (__bf16)v[0];
    T[r][q * 16 + u * 4 + 1] = (__bf16)v[1];
    T[r][q * 16 + u * 4 + 2] = (__bf16)v[2];
    T[r][q * 16 + u * 4 + 3] = (__bf16)v[3];
  }
  __syncthreads();
  bf16x8 h0, h1;
#pragma unroll
  for (int u = 0; u < 8; ++u) {
    h0[u] = T[q * 16 + u][r];      // k = bi*64+q*16+u,   n = bj*64+r
    h1[u] = T[q * 16 + 8 + u][r];  // k = bi*64+q*16+8+u
  }
  // element (n,k) -> [(k>>3)*256 + n]*8 + (k&7)
  __bf16* d0 = Wt + ((size_t)(bi * 8 + q * 2) * 256 + (bj * 64 + r)) * 8;
  *(bf16x8*)d0          = h0;
  *(bf16x8*)(d0 + 2048) = h1;
}

// ---- main GEMM: 128x256 tile, BK=64, 512 thr (8 waves 2x4) -----------------
// EPI_ST=true : epilogue -> St k-subtiled bf16 (gemm1: feat @ W)
// EPI_ST=false: epilogue -> Out fp32 + bias, XCD swizzle (gemm2)
template <int KTOT, int LDA, bool EPI_ST>
__global__ __launch_bounds__(512, 2) void k_gemm(
    const float* __restrict__ Aall, const __bf16* __restrict__ Bg_all,
    const float* __restrict__ bias, float* __restrict__ Out,
    __bf16* __restrict__ St) {
  __shared__ __bf16 Af[2][128 * 64];     // 16 KB each: [row][slot^(row&7)][8]
  __shared__ __bf16 Bf[2][8 * 256 * 8];  // 32 KB each: [chunk][n][8]

  const int tid  = threadIdx.x;
  const int lane = tid & 63;
  const int wid  = tid >> 6;       // 0..7
  const int wr   = wid >> 2;       // 0..1 -> m offset *64
  const int wc   = wid & 3;        // 0..3 -> n offset *64
  const int l16  = lane & 15;
  const int g    = lane >> 4;      // 0..3

  int b, mblk;
  const float*  Ablk;
  const __bf16* Bblk;
  if constexpr (EPI_ST) {
    const int bx = blockIdx.x;     // 256 blocks: feat rows globally contiguous
    b    = bx >> 3;
    mblk = bx & 7;
    Ablk = Aall + (size_t)bx * 128 * LDA;
    Bblk = Bg_all;                 // Wt
  } else {
    const int h  = blockIdx.x;     // 256 % 8 == 0: bijective XCD swizzle
    const int lg = (h & 7) * 32 + (h >> 3);  // XCD x owns batches 4x..4x+3
    b    = lg >> 3;
    mblk = lg & 7;
    Ablk = Aall + (size_t)b * 1024 * 1024 + (size_t)mblk * 128 * LDA;
    Bblk = Bg_all + (size_t)b * 262144;      // St[b], k-subtiled
  }

  // --- A staging (reg): thread t -> row=t>>2, k-cols (t&3)*16..+15 ---
  const int    srow = tid >> 2;
  const int    sq   = tid & 3;
  const float* asrc = Ablk + (size_t)srow * LDA + sq * 16;
  // swizzled LDS element offsets for the two 8-elem slots (s0=2q, s1=2q+1)
  const int wof0 = srow * 64 + (((sq * 2)     ^ (srow & 7)) << 3);
  const int wof1 = srow * 64 + (((sq * 2 + 1) ^ (srow & 7)) << 3);

  // --- B staging (DMA): thread t handles chunks {i*512+t} of 16 B ---
  const __bf16* bS[4];
#pragma unroll
  for (int i = 0; i < 4; ++i) bS[i] = Bblk + (size_t)(i * 512 + tid) * 8;

#define LOADA(S, k0)                                                          \
  {                                                                           \
    _Pragma("unroll") for (int u = 0; u < 4; ++u)                             \
        S[u] = *(const f32x4*)(asrc + (k0) + u * 4);                          \
  }
#define ISSUEB(buf, k0)                                                       \
  {                                                                           \
    const size_t koff = (size_t)((k0) >> 3) * 2048;                           \
    _Pragma("unroll") for (int i = 0; i < 4; ++i)                             \
        gld16(bS[i] + koff, &Bf[buf][(i * 512 + wid * 64) * 8]);              \
    asm volatile("" ::: "memory"); /* pin: later loads can't hoist above */   \
  }
#define CVTW(S, buf)                                                          \
  {                                                                           \
    bf16x8 h0 = {(__bf16)S[0][0], (__bf16)S[0][1], (__bf16)S[0][2],           \
                 (__bf16)S[0][3], (__bf16)S[1][0], (__bf16)S[1][1],           \
                 (__bf16)S[1][2], (__bf16)S[1][3]};                           \
    bf16x8 h1 = {(__bf16)S[2][0], (__bf16)S[2][1], (__bf16)S[2][2],           \
                 (__bf16)S[2][3], (__bf16)S[3][0], (__bf16)S[3][1],           \
                 (__bf16)S[3][2], (__bf16)S[3][3]};                           \
    *(bf16x8*)&Af[buf][wof0] = h0;                                            \
    *(bf16x8*)&Af[buf][wof1] = h1;                                            \
  }
// counted sync: B(t+1) (oldest 4 vmem) done; A(t+2) (newest 4) keeps flying
#define SYNC_STEP                                                             \
  asm volatile("s_waitcnt vmcnt(4) lgkmcnt(0)\n\ts_barrier" ::: "memory")
#define SYNC_LAST                                                             \
  asm volatile("s_waitcnt vmcnt(0) lgkmcnt(0)\n\ts_barrier" ::: "memory")

  f32x4 S0[4], S1[4];

  f32x4 acc[4][4];
#pragma unroll
  for (int m = 0; m < 4; ++m)
#pragma unroll
    for (int n = 0; n < 4; ++n) acc[m][n] = (f32x4){0.f, 0.f, 0.f, 0.f};

  auto compute = [&](int buf) {
#pragma unroll
    for (int ks = 0; ks < 2; ++ks) {
      bf16x8 af[4], bv[4];
#pragma unroll
      for (int m = 0; m < 4; ++m) {
        const int row  = wr * 64 + m * 16 + l16;
        const int slot = (ks * 4 + g) ^ (row & 7);
        af[m] = *(const bf16x8*)&Af[buf][row * 64 + slot * 8];
      }
#pragma unroll
      for (int n = 0; n < 4; ++n) {
        const int col = wc * 64 + n * 16 + l16;
        bv[n] = *(const bf16x8*)&Bf[buf][((ks * 4 + g) * 256 + col) * 8];
      }
      __builtin_amdgcn_s_setprio(1);
#pragma unroll
      for (int m = 0; m < 4; ++m)
#pragma unroll
        for (int n = 0; n < 4; ++n)
          acc[m][n] = __builtin_amdgcn_mfma_f32_16x16x32_bf16(af[m], bv[n], acc[m][n], 0, 0, 0);
      __builtin_amdgcn_s_setprio(0);
    }
  };

  constexpr int NT = KTOT / BK;    // 16 (gemm2) or 4 (gemm1), even
  // prologue: A(t0)->LDS0, B(t0) DMA, A(t1)->regs; counted sync; B(t1) DMA
  LOADA(S0, 0);
  ISSUEB(0, 0);
  CVTW(S0, 0);                     // compiler waits A(t0) regs, ds_writes
  LOADA(S1, BK);
  SYNC_STEP;                       // B(t0) arrived; A(t1) still flying
  ISSUEB(1, BK);

  for (int t = 0; t < NT - 2; t += 2) {
    compute(0);                    // tile t
    CVTW(S1, 1);                   // A(t+1) -> LDS[1]
    LOADA(S0, (t + 2) * BK);       // A(t+2) -> regs (flies through sync)
    SYNC_STEP;                     // B(t+1) arrived -> tile t+1 ready
    ISSUEB(0, (t + 2) * BK);       // buf0 free now (everyone done reading)

    compute(1);                    // tile t+1
    CVTW(S0, 0);                   // A(t+2) -> LDS[0]
    LOADA(S1, (t + 3) * BK);       // A(t+3)
    SYNC_STEP;                     // B(t+2) arrived
    ISSUEB(1, (t + 3) * BK);
  }
  compute(0);                      // tile NT-2
  CVTW(S1, 1);                     // A(NT-1) -> LDS[1]
  SYNC_LAST;                       // drain B(NT-1)
  compute(1);                      // tile NT-1

#undef LOADA
#undef ISSUEB
#undef CVTW
#undef SYNC_STEP
#undef SYNC_LAST

  // --- epilogue. C/D frag: col = lane&15, row = (lane>>4)*4 + reg ---
  const int rg = g * 4;
  if constexpr (EPI_ST) {
    __bf16* Stb = St + (size_t)b * 262144;
    const int gm0 = mblk * 128 + wr * 64;
#pragma unroll
    for (int n = 0; n < 4; ++n) {
      const int col = wc * 64 + n * 16 + l16;
#pragma unroll
      for (int m = 0; m < 4; ++m) {
        const int gm = gm0 + m * 16 + rg;   // multiple of 4; gm&7 in {0,4}
        __bf16* dst = Stb + (size_t)(gm >> 3) * 2048 + (size_t)col * 8 + (gm & 7);
        bf16x4 hh = {(__bf16)acc[m][n][0], (__bf16)acc[m][n][1],
                     (__bf16)acc[m][n][2], (__bf16)acc[m][n][3]};
        *(bf16x4*)dst = hh;
      }
    }
  } else {
    float* ob = Out + ((size_t)b * 1024 + (size_t)mblk * 128 + wr * 64) * 256;
#pragma unroll
    for (int n = 0; n < 4; ++n) {
      const int col = wc * 64 + n * 16 + l16;
      const float bvs = bias[col];
#pragma unroll
      for (int m = 0; m < 4; ++m) {
        const int row = m * 16 + rg;
#pragma unroll
        for (int r2 = 0; r2 < 4; ++r2)
          ob[(size_t)(row + r2) * 256 + col] = acc[m][n][r2] + bvs;
      }
    }
  }
}

extern "C" void kernel_launch(void* const* d_in, const int* in_sizes, int n_in,
                              void* d_out, int out_size, void* d_ws, size_t ws_size,
                              hipStream_t stream) {
  const float* adj  = (const float*)d_in[0];
  const float* feat = (const float*)d_in[1];
  const float* w    = (const float*)d_in[2];
  const float* bias = (const float*)d_in[3];
  float* out = (float*)d_out;

  __bf16* Wt = (__bf16*)d_ws;                    // 128 KB
  __bf16* St = (__bf16*)((char*)d_ws + 131072);  // 16.78 MB

  k_wt<<<16, 256, 0, stream>>>(w, Wt);
  // gemm1: St = (feat @ W), k-subtiled output  (K=256, A ld 256)
  k_gemm<256, 256, true><<<256, 512, 0, stream>>>(feat, Wt, nullptr, nullptr, St);
  // gemm2: out = adj @ support + bias          (K=1024, A ld 1024)
  k_gemm<1024, 1024, false><<<256, 512, 0, stream>>>(adj, St, bias, out, nullptr);
}